// Round 3
// baseline (460.307 us; speedup 1.0000x reference)
//
#include <hip/hip_runtime.h>
#include <hip/hip_bf16.h>

// SpatialContextNet on MI355X (gfx950). Round 6.
// - GEMM: exact Round-4 kernel (93us verified; 4-phase BK=64 pipeline).
// - scn_transpose DELETED: corr_part now also emits the At center block
//   (it already loads every feature value it needs). Per 64-ch half:
//   stash f2bf(ctr) in LDS ushort[512][66] (132B row stride: 2-way write
//   banks, conflict-free 4xb32 reads), then cooperative 128B-coalesced
//   At stores. Saves one full 134MB feature read + a kernel launch.
// - Other aux kernels: Round-4 versions (CS=8).
//
// feature [8,1024,64,64] f32, conv_w [1024,1049] f32, conv_b [1024] f32.
// Out [8,1024,64,64] f32.

typedef __attribute__((ext_vector_type(8))) short short8x;
typedef __attribute__((ext_vector_type(4))) float floatx4;

#define B_   8
#define C_   1024
#define HW_  4096
#define KPAD 1088
#define NT   17

__device__ __forceinline__ unsigned short f2bf(float f) {
  unsigned int u = __float_as_uint(f);
  u += 0x7FFFu + ((u >> 16) & 1u);
  return (unsigned short)(u >> 16);
}

__device__ __forceinline__ void async16(const void* g, void* l) {
  __builtin_amdgcn_global_load_lds(
      (__attribute__((address_space(1))) void*)(void*)g,
      (__attribute__((address_space(3))) void*)l, 16, 0, 0);
}

__device__ __forceinline__ short8x rd16(const char* p) {
  return *(const short8x*)p;
}

// ---- K1: correlation partials + At center write (fused transpose) ----------
// grid (8 ystrips, 8 cs, 8 b), block 512 (8 waves = 8 rows).
// part[(cs*25+j)*32768 + b*4096 + y*64 + x]  (f32)
// At[b][m][k] center block [m0..m0+512) x [cs*128..+128) written here.
__global__ __launch_bounds__(512) void scn_corr_part(
    const float* __restrict__ f, float* __restrict__ part,
    unsigned short* __restrict__ At) {
  // LDS transpose buffer: [512 m][66 shorts] (132B stride).
  // write banks: (tid + c/2) % 32 -> 2-way (free). reads: 4xb32, conflict-free.
  __shared__ unsigned short lct[512][66];

  const int tid = threadIdx.x;
  const int x = tid & 63;
  const int y = blockIdx.x * 8 + (tid >> 6);
  const int cs = blockIdx.y, b = blockIdx.z;

  const int xs0 = (x + 2 < 64) ? x + 2 : 63;
  const int xs1 = (x + 1 < 64) ? x + 1 : 63;
  const int xs3 = (x - 1 >= 0) ? x - 1 : 0;
  const int xs4 = (x - 2 >= 0) ? x - 2 : 0;

  const bool ym2 = (y >= 2), ym1 = (y >= 1), yp1 = (y <= 62), yp2 = (y <= 61);

  const float* rp0 = f + ((size_t)b * C_ + cs * 128) * HW_ + y * 64;

  float h[25];
#pragma unroll
  for (int j = 0; j < 25; ++j) h[j] = 0.f;

  unsigned short* const lrow = &lct[tid][0];
  const int m0 = blockIdx.x * 512;
  const int cslice = tid & 7, mbase = tid >> 3;

  for (int half = 0; half < 2; ++half) {
#pragma unroll 4
    for (int c64 = 0; c64 < 64; ++c64) {
      const int c = half * 64 + c64;
      const float* rp = rp0 + (size_t)c * HW_;
      const float ctr = rp[x];
      const float vm2 = ym2 ? rp[x - 128] : 0.f;
      const float vm1 = ym1 ? rp[x - 64] : 0.f;
      const float vp1 = yp1 ? rp[x + 64] : 0.f;
      const float vp2 = yp2 ? rp[x + 128] : 0.f;
      const float c0 = rp[xs0], c1 = rp[xs1], c3 = rp[xs3], c4 = rp[xs4];
      lrow[c64] = f2bf(ctr);  // stash for At write
      const float v[5] = {vm2, vm1, ctr, vp1, vp2};
      const float cc[5] = {c0, c1, ctr, c3, c4};
#pragma unroll
      for (int dxi = 0; dxi < 5; ++dxi)
#pragma unroll
        for (int dyi = 0; dyi < 5; ++dyi)
          h[dxi * 5 + dyi] = fmaf(v[dyi], cc[dxi], h[dxi * 5 + dyi]);
    }
    __syncthreads();
    // cooperative At store: lanes 0..7 -> same mm, cslice 0..7 => 128B segs
    const int k0 = cs * 128 + half * 64;
#pragma unroll
    for (int g = 0; g < 8; ++g) {
      const int mm = mbase + g * 64;
      const unsigned int* p =
          (const unsigned int*)((const char*)&lct[mm][0] + cslice * 16);
      unsigned int w0 = p[0], w1 = p[1], w2 = p[2], w3 = p[3];
      unsigned int* dst = (unsigned int*)(At + ((size_t)b * HW_ + m0 + mm) * KPAD +
                                          k0 + cslice * 8);
      dst[0] = w0; dst[1] = w1; dst[2] = w2; dst[3] = w3;
    }
    __syncthreads();
  }

  float* pb = part + (size_t)(cs * 25) * 32768 + b * HW_ + y * 64;
#pragma unroll
  for (int j = 0; j < 25; ++j) {
    const int dx = (j / 5) - 2;
    const int tgt = x - dx;
    const int wx = (tgt + 64) & 63;
    const float val = ((unsigned)tgt < 64u) ? h[j] : 0.f;
    pb[(size_t)j * 32768 + wx] = val;
  }
}

// ---- K3: inv norm from j=12 partial slices ---------------------------------
__global__ __launch_bounds__(256) void scn_invn(const float* __restrict__ part,
                                                float* __restrict__ invn) {
  const int i = blockIdx.x * 256 + threadIdx.x;
  float s = 0.f;
#pragma unroll
  for (int cs = 0; cs < 8; ++cs) s += part[(size_t)(cs * 25 + 12) * 32768 + i];
  invn[i] = 1.0f / fmaxf(sqrtf(s), 1e-12f);
}

// ---- K4: reduce partials over cs, apply norms, write At rows 1024..1087 ----
__global__ __launch_bounds__(256) void scn_corr_reduce(
    const float* __restrict__ part, const float* __restrict__ invn,
    unsigned short* __restrict__ At) {
  const int b = blockIdx.y;
  const int m = blockIdx.x * 256 + threadIdx.x;
  const int i = b * HW_ + m;
  const int y = m >> 6, x = m & 63;

  float acc[25];
#pragma unroll
  for (int j = 0; j < 25; ++j) acc[j] = 0.f;
#pragma unroll 1
  for (int cs = 0; cs < 8; ++cs) {
    const float* pb = part + (size_t)(cs * 25) * 32768 + i;
#pragma unroll
    for (int j = 0; j < 25; ++j) acc[j] += pb[(size_t)j * 32768];
  }
  const float ic = invn[i];
  unsigned short r[64];
#pragma unroll
  for (int j = 0; j < 25; ++j) {
    const int dy = (j % 5) - 2, dx = (j / 5) - 2;
    const int ny = y + dy, nx = x + dx;
    float in2 = (ny >= 0 && ny < 64 && nx >= 0 && nx < 64)
                    ? invn[b * HW_ + (ny << 6) + nx] : 0.f;
    r[j] = f2bf(acc[j] * ic * in2);
  }
#pragma unroll
  for (int j = 25; j < 64; ++j) r[j] = 0;
  unsigned short* row = At + ((size_t)b * HW_ + m) * KPAD + 1024;
#pragma unroll
  for (int v = 0; v < 8; ++v) *(short8x*)(row + v * 8) = *(short8x*)(r + v * 8);
}

// ---- K5: cast+pad conv_w -> Wb [1024][1088] bf16 ---------------------------
__global__ __launch_bounds__(256) void scn_wcast(const float* __restrict__ w,
                                                 unsigned short* __restrict__ Wb) {
  const int i = blockIdx.x * 256 + threadIdx.x;
  const int o = i / KPAD, k = i - o * KPAD;
  Wb[i] = (k < 1049) ? f2bf(w[(size_t)o * 1049 + k]) : 0;
}

// ---- K6: bf16 MFMA GEMM 256x256/BK=64, pipelined (exact Round-4 kernel) ----
// grid (16 nb, 4 ob, 8 b), block 512 (8 waves: wm = wid>>2, wn = wid&3).
// LDS 128 KiB: buf[2] x { A: 2 halves x [128][64] ; B: same }, bf16.
// Staging: global_load_lds, linear dest, inverse-swizzled global source.
// Read swizzle: 16B slot ^= (row&7). Counted vmcnt(8), raw s_barrier only.
__global__ __launch_bounds__(512, 2) void scn_gemm(
    const unsigned short* __restrict__ Wb, const unsigned short* __restrict__ At,
    const float* __restrict__ bias, float* __restrict__ out) {
  extern __shared__ char lds[];
  const int tid = threadIdx.x;
  const int l = tid & 63;
  const int wid = tid >> 6;
  const int wm = wid >> 2;   // M half (128 rows of W)
  const int wn = wid & 3;    // N quarter (64 rows of At)
  const int nb = blockIdx.x, ob = blockIdx.y, b = blockIdx.z;

  const int rr = tid >> 3;
  const int cswz = ((tid & 7) ^ (rr & 7)) << 3;
  const unsigned short* gA = Wb + (size_t)(ob * 256 + rr) * KPAD + cswz;
  const unsigned short* gB = At + ((size_t)b * HW_ + nb * 256 + rr) * KPAD + cswz;
  char* const dBase = (char*)lds + tid * 16;

#define ISSUE_A(bf, kt)                                         \
  do {                                                          \
    const unsigned short* _s = gA + (kt) * 64;                  \
    char* _d = dBase + (bf) * 65536;                            \
    async16(_s, _d);                                            \
    async16(_s + (size_t)64 * KPAD, _d + 8192);                 \
    async16(_s + (size_t)128 * KPAD, _d + 16384);               \
    async16(_s + (size_t)192 * KPAD, _d + 24576);               \
  } while (0)

#define ISSUE_B(bf, kt)                                         \
  do {                                                          \
    const unsigned short* _s = gB + (kt) * 64;                  \
    char* _d = dBase + (bf) * 65536 + 32768;                    \
    async16(_s, _d);                                            \
    async16(_s + (size_t)64 * KPAD, _d + 8192);                 \
    async16(_s + (size_t)128 * KPAD, _d + 16384);               \
    async16(_s + (size_t)192 * KPAD, _d + 24576);               \
  } while (0)

  const int l15 = l & 15, l4g = l >> 4, l7 = l & 7;
  const int aoff0 = l15 * 128 + ((l4g ^ l7) << 4);
  const int aoff1 = l15 * 128 + (((l4g + 4) ^ l7) << 4);
  const char* aB0 = (const char*)lds + wm * 16384;
  const char* bB0 = (const char*)lds + 32768 + (wn >> 1) * 16384 + (wn & 1) * 8192;

  floatx4 acc[8][4];
#pragma unroll
  for (int i = 0; i < 8; ++i)
#pragma unroll
    for (int j = 0; j < 4; ++j) acc[i][j] = (floatx4){0.f, 0.f, 0.f, 0.f};

  ISSUE_A(0, 0); ISSUE_B(0, 0);
  ISSUE_A(1, 1); ISSUE_B(1, 1);
  asm volatile("s_waitcnt vmcnt(8)" ::: "memory");
  __builtin_amdgcn_s_barrier();

  short8x a[4][2], b0[2][2], b1[2][2];

  for (int t = 0; t < NT; ++t) {
    const int bf = t & 1;
    const char* ab = aB0 + bf * 65536;
    const char* bb = bB0 + bf * 65536;
    const int t2 = (t < NT - 2) ? (t + 2) : 0;

    // ---- P1: read Aq0 + Bh0; MFMA Q00 ----
#pragma unroll
    for (int i = 0; i < 4; ++i) {
      a[i][0] = rd16(ab + i * 2048 + aoff0);
      a[i][1] = rd16(ab + i * 2048 + aoff1);
    }
#pragma unroll
    for (int j = 0; j < 2; ++j) {
      b0[j][0] = rd16(bb + j * 2048 + aoff0);
      b0[j][1] = rd16(bb + j * 2048 + aoff1);
    }
    __builtin_amdgcn_s_barrier();
    asm volatile("s_waitcnt lgkmcnt(0)" ::: "memory");
    __builtin_amdgcn_sched_barrier(0);
    __builtin_amdgcn_s_setprio(1);
#pragma unroll
    for (int i = 0; i < 4; ++i)
#pragma unroll
      for (int j = 0; j < 2; ++j) {
        acc[i][j] = __builtin_amdgcn_mfma_f32_16x16x32_bf16(a[i][0], b0[j][0], acc[i][j], 0, 0, 0);
        acc[i][j] = __builtin_amdgcn_mfma_f32_16x16x32_bf16(a[i][1], b0[j][1], acc[i][j], 0, 0, 0);
      }
    __builtin_amdgcn_s_setprio(0);
    __builtin_amdgcn_s_barrier();

    // ---- P2: read Bh1; MFMA Q01 ----
#pragma unroll
    for (int j = 0; j < 2; ++j) {
      b1[j][0] = rd16(bb + (2 + j) * 2048 + aoff0);
      b1[j][1] = rd16(bb + (2 + j) * 2048 + aoff1);
    }
    __builtin_amdgcn_s_barrier();
    asm volatile("s_waitcnt lgkmcnt(0)" ::: "memory");
    __builtin_amdgcn_sched_barrier(0);
    __builtin_amdgcn_s_setprio(1);
#pragma unroll
    for (int i = 0; i < 4; ++i)
#pragma unroll
      for (int j = 0; j < 2; ++j) {
        acc[i][2 + j] = __builtin_amdgcn_mfma_f32_16x16x32_bf16(a[i][0], b1[j][0], acc[i][2 + j], 0, 0, 0);
        acc[i][2 + j] = __builtin_amdgcn_mfma_f32_16x16x32_bf16(a[i][1], b1[j][1], acc[i][2 + j], 0, 0, 0);
      }
    __builtin_amdgcn_s_setprio(0);
    __builtin_amdgcn_s_barrier();

    // ---- P3: read Aq1; issue B(t+2); MFMA Q11 ----
#pragma unroll
    for (int i = 0; i < 4; ++i) {
      a[i][0] = rd16(ab + (4 + i) * 2048 + aoff0);
      a[i][1] = rd16(ab + (4 + i) * 2048 + aoff1);
    }
    ISSUE_B(bf, t2);
    __builtin_amdgcn_s_barrier();
    asm volatile("s_waitcnt lgkmcnt(0)" ::: "memory");
    __builtin_amdgcn_sched_barrier(0);
    __builtin_amdgcn_s_setprio(1);
#pragma unroll
    for (int i = 0; i < 4; ++i)
#pragma unroll
      for (int j = 0; j < 2; ++j) {
        acc[4 + i][2 + j] = __builtin_amdgcn_mfma_f32_16x16x32_bf16(a[i][0], b1[j][0], acc[4 + i][2 + j], 0, 0, 0);
        acc[4 + i][2 + j] = __builtin_amdgcn_mfma_f32_16x16x32_bf16(a[i][1], b1[j][1], acc[4 + i][2 + j], 0, 0, 0);
      }
    __builtin_amdgcn_s_setprio(0);
    __builtin_amdgcn_s_barrier();

    // ---- P4: issue A(t+2); MFMA Q10; counted vmcnt(8) ----
    ISSUE_A(bf, t2);
    __builtin_amdgcn_s_barrier();
    __builtin_amdgcn_s_setprio(1);
#pragma unroll
    for (int i = 0; i < 4; ++i)
#pragma unroll
      for (int j = 0; j < 2; ++j) {
        acc[4 + i][j] = __builtin_amdgcn_mfma_f32_16x16x32_bf16(a[i][0], b0[j][0], acc[4 + i][j], 0, 0, 0);
        acc[4 + i][j] = __builtin_amdgcn_mfma_f32_16x16x32_bf16(a[i][1], b0[j][1], acc[4 + i][j], 0, 0, 0);
      }
    __builtin_amdgcn_s_setprio(0);
    asm volatile("s_waitcnt vmcnt(8)" ::: "memory");
    __builtin_amdgcn_s_barrier();
  }
  asm volatile("s_waitcnt vmcnt(0)" ::: "memory");
#undef ISSUE_A
#undef ISSUE_B

  float* outb = out + (size_t)b * C_ * HW_;
#pragma unroll
  for (int i = 0; i < 8; ++i) {
    const int o0 = ob * 256 + wm * 128 + i * 16 + l4g * 4;
    float bs[4];
#pragma unroll
    for (int r = 0; r < 4; ++r) bs[r] = bias[o0 + r];
#pragma unroll
    for (int j = 0; j < 4; ++j) {
      const int m = nb * 256 + wn * 64 + j * 16 + l15;
#pragma unroll
      for (int r = 0; r < 4; ++r) {
        float v = acc[i][j][r] + bs[r];
        outb[(size_t)(o0 + r) * HW_ + m] = v > 0.f ? v : 0.f;
      }
    }
  }
}

// ---- launch ----------------------------------------------------------------
extern "C" void kernel_launch(void* const* d_in, const int* in_sizes, int n_in,
                              void* d_out, int out_size, void* d_ws, size_t ws_size,
                              hipStream_t stream) {
  const float* feature = (const float*)d_in[0];
  const float* conv_w  = (const float*)d_in[1];
  const float* conv_b  = (const float*)d_in[2];
  float* out = (float*)d_out;

  // workspace layout (bytes), total 97,648,640:
  //   At   [32768][1088] bf16 : 0          .. 71,303,168
  //   part [8*25][32768] f32  : 71,303,168 .. 97,517,568
  //   Wb   [1024][1088] bf16  : aliases part (part dead after corr_reduce)
  //   invn [32768] f32        : 97,517,568 .. 97,648,640
  char* ws = (char*)d_ws;
  unsigned short* At = (unsigned short*)(ws);
  float* part        = (float*)(ws + 71303168);
  unsigned short* Wb = (unsigned short*)(ws + 71303168);  // aliases part
  float* invn        = (float*)(ws + 97517568);

  static int gemm_attr_set = 0;
  if (!gemm_attr_set) {
    hipFuncSetAttribute((const void*)scn_gemm,
                        hipFuncAttributeMaxDynamicSharedMemorySize, 131072);
    gemm_attr_set = 1;
  }

  scn_corr_part<<<dim3(8, 8, 8), 512, 0, stream>>>(feature, part, At);
  scn_invn<<<dim3(128), 256, 0, stream>>>(part, invn);
  scn_corr_reduce<<<dim3(16, 8), 256, 0, stream>>>(part, invn, At);
  scn_wcast<<<dim3((1024 * KPAD) / 256), 256, 0, stream>>>(conv_w, Wb);
  scn_gemm<<<dim3(16, 4, 8), 512, 131072, stream>>>(Wb, At, conv_b, out);
}

// Round 4
// 388.268 us; speedup vs baseline: 1.1855x; 1.1855x over previous
//
#include <hip/hip_runtime.h>
#include <hip/hip_bf16.h>

// SpatialContextNet on MI355X (gfx950). Round 7.
// Best-known base = Round 4 (383us). Changes vs R4:
//  - scn_corr_part + scn_transpose merged into ONE launch (scn_aux) with
//    role-partitioned blocks interleaved 1:8 for CU co-residency:
//    corr is latency-bound (18% VALU, 12% HBM), transpose is BW-bound ->
//    concurrent execution approaches max() instead of sum(). Bodies are
//    verbatim R4 (no intra-block fusion -- that was R6's 203us mistake).
//  - corr role: 4 horizontal neighbor loads replaced by __shfl of ctr
//    (same row lives in the wave; bit-exact clamped value). VMEM 9->5/ch.
//  - GEMM / invn / reduce / wcast: exact R4 kernels. wcast stays a separate
//    launch after reduce (Wb aliases part).
//
// feature [8,1024,64,64] f32, conv_w [1024,1049] f32, conv_b [1024] f32.
// Out [8,1024,64,64] f32.

typedef __attribute__((ext_vector_type(8))) short short8x;
typedef __attribute__((ext_vector_type(4))) float floatx4;

#define B_   8
#define C_   1024
#define HW_  4096
#define KPAD 1088
#define NT   17

__device__ __forceinline__ unsigned short f2bf(float f) {
  unsigned int u = __float_as_uint(f);
  u += 0x7FFFu + ((u >> 16) & 1u);
  return (unsigned short)(u >> 16);
}

__device__ __forceinline__ void async16(const void* g, void* l) {
  __builtin_amdgcn_global_load_lds(
      (__attribute__((address_space(1))) void*)(void*)g,
      (__attribute__((address_space(3))) void*)l, 16, 0, 0);
}

__device__ __forceinline__ short8x rd16(const char* p) {
  return *(const short8x*)p;
}

// ---- K1: merged aux kernel: corr partials + transpose-cast -----------------
// 4608 blocks x 512 threads. n%9==0 -> corr block g=n/9 (512 blocks);
// else transpose block g*8+(n%9-1) (4096 blocks, 2 tiles each).
// corr:  part[(cs*25+j)*32768 + b*4096 + y*64 + x]  (f32), rotated store.
// trans: At[b][m][k] center columns, 64x64 tiles via LDS.
__global__ __launch_bounds__(512) void scn_aux(
    const float* __restrict__ f, float* __restrict__ part,
    unsigned short* __restrict__ At) {
  __shared__ float lds2[2][64][65];
  const int n = blockIdx.x;
  const int g = n / 9, r = n - g * 9;
  const int tid = threadIdx.x;

  if (r == 0) {
    // ================= corr role (verbatim R4 + shfl horizontals) ==========
    const int x = tid & 63;
    const int y = (g & 7) * 8 + (tid >> 6);
    const int cs = (g >> 3) & 7, b = g >> 6;

    const int xs0 = (x + 2 < 64) ? x + 2 : 63;
    const int xs1 = (x + 1 < 64) ? x + 1 : 63;
    const int xs3 = (x - 1 >= 0) ? x - 1 : 0;
    const int xs4 = (x - 2 >= 0) ? x - 2 : 0;

    const bool ym2 = (y >= 2), ym1 = (y >= 1), yp1 = (y <= 62), yp2 = (y <= 61);

    const float* rp0 = f + ((size_t)b * C_ + cs * 128) * HW_ + y * 64;

    float h[25];
#pragma unroll
    for (int j = 0; j < 25; ++j) h[j] = 0.f;

#pragma unroll 4
    for (int c = 0; c < 128; ++c) {
      const float* rp = rp0 + (size_t)c * HW_;
      const float ctr = rp[x];
      const float vm2 = ym2 ? rp[x - 128] : 0.f;
      const float vm1 = ym1 ? rp[x - 64] : 0.f;
      const float vp1 = yp1 ? rp[x + 64] : 0.f;
      const float vp2 = yp2 ? rp[x + 128] : 0.f;
      // horizontal neighbors: same row, held by sibling lanes (wave = row).
      const float c0 = __shfl(ctr, xs0, 64);
      const float c1 = __shfl(ctr, xs1, 64);
      const float c3 = __shfl(ctr, xs3, 64);
      const float c4 = __shfl(ctr, xs4, 64);
      const float v[5] = {vm2, vm1, ctr, vp1, vp2};
      const float cc[5] = {c0, c1, ctr, c3, c4};
#pragma unroll
      for (int dxi = 0; dxi < 5; ++dxi)
#pragma unroll
        for (int dyi = 0; dyi < 5; ++dyi)
          h[dxi * 5 + dyi] = fmaf(v[dyi], cc[dxi], h[dxi * 5 + dyi]);
    }

    float* pb = part + (size_t)(cs * 25) * 32768 + b * HW_ + y * 64;
#pragma unroll
    for (int j = 0; j < 25; ++j) {
      const int dx = (j / 5) - 2;
      const int tgt = x - dx;
      const int wx = (tgt + 64) & 63;
      const float val = ((unsigned)tgt < 64u) ? h[j] : 0.f;
      pb[(size_t)j * 32768 + wx] = val;
    }
  } else {
    // ================= transpose role (verbatim R4, 2 tiles/block) =========
    const int half = tid >> 8, t256 = tid & 255;
    const int tile = (g * 8 + (r - 1)) * 2 + half;
    const int b = tile >> 10, rem = tile & 1023;
    const int kt = rem >> 6, mt = rem & 63;

    const float* src = f + ((size_t)b * C_ + kt * 64) * HW_ + mt * 64;
    const int mi = t256 & 63, kr = t256 >> 6;
#pragma unroll
    for (int i = 0; i < 16; ++i)
      lds2[half][kr + i * 4][mi] = src[(size_t)(kr + i * 4) * HW_ + mi];
    __syncthreads();
    unsigned short* dst = At + ((size_t)b * HW_ + mt * 64) * KPAD + kt * 64;
    const int c = t256 & 7, mr = t256 >> 3;
#pragma unroll
    for (int h2 = 0; h2 < 2; ++h2) {
      const int mm = mr + h2 * 32;
      short8x v;
#pragma unroll
      for (int j = 0; j < 8; ++j) v[j] = (short)f2bf(lds2[half][c * 8 + j][mm]);
      *(short8x*)(dst + (size_t)mm * KPAD + c * 8) = v;
    }
  }
}

// ---- K3: inv norm from j=12 partial slices ---------------------------------
__global__ __launch_bounds__(256) void scn_invn(const float* __restrict__ part,
                                                float* __restrict__ invn) {
  const int i = blockIdx.x * 256 + threadIdx.x;
  float s = 0.f;
#pragma unroll
  for (int cs = 0; cs < 8; ++cs) s += part[(size_t)(cs * 25 + 12) * 32768 + i];
  invn[i] = 1.0f / fmaxf(sqrtf(s), 1e-12f);
}

// ---- K4: reduce partials over cs, apply norms, write At rows 1024..1087 ----
__global__ __launch_bounds__(256) void scn_corr_reduce(
    const float* __restrict__ part, const float* __restrict__ invn,
    unsigned short* __restrict__ At) {
  const int b = blockIdx.y;
  const int m = blockIdx.x * 256 + threadIdx.x;
  const int i = b * HW_ + m;
  const int y = m >> 6, x = m & 63;

  float acc[25];
#pragma unroll
  for (int j = 0; j < 25; ++j) acc[j] = 0.f;
#pragma unroll 1
  for (int cs = 0; cs < 8; ++cs) {
    const float* pb = part + (size_t)(cs * 25) * 32768 + i;
#pragma unroll
    for (int j = 0; j < 25; ++j) acc[j] += pb[(size_t)j * 32768];
  }
  const float ic = invn[i];
  unsigned short r[64];
#pragma unroll
  for (int j = 0; j < 25; ++j) {
    const int dy = (j % 5) - 2, dx = (j / 5) - 2;
    const int ny = y + dy, nx = x + dx;
    float in2 = (ny >= 0 && ny < 64 && nx >= 0 && nx < 64)
                    ? invn[b * HW_ + (ny << 6) + nx] : 0.f;
    r[j] = f2bf(acc[j] * ic * in2);
  }
#pragma unroll
  for (int j = 25; j < 64; ++j) r[j] = 0;
  unsigned short* row = At + ((size_t)b * HW_ + m) * KPAD + 1024;
#pragma unroll
  for (int v = 0; v < 8; ++v) *(short8x*)(row + v * 8) = *(short8x*)(r + v * 8);
}

// ---- K5: cast+pad conv_w -> Wb [1024][1088] bf16 ---------------------------
__global__ __launch_bounds__(256) void scn_wcast(const float* __restrict__ w,
                                                 unsigned short* __restrict__ Wb) {
  const int i = blockIdx.x * 256 + threadIdx.x;
  const int o = i / KPAD, k = i - o * KPAD;
  Wb[i] = (k < 1049) ? f2bf(w[(size_t)o * 1049 + k]) : 0;
}

// ---- K6: bf16 MFMA GEMM 256x256/BK=64, pipelined (exact Round-4 kernel) ----
// grid (16 nb, 4 ob, 8 b), block 512 (8 waves: wm = wid>>2, wn = wid&3).
// LDS 128 KiB: buf[2] x { A: 2 halves x [128][64] ; B: same }, bf16.
// Staging: global_load_lds, linear dest, inverse-swizzled global source.
// Read swizzle: 16B slot ^= (row&7). Counted vmcnt(8), raw s_barrier only.
__global__ __launch_bounds__(512, 2) void scn_gemm(
    const unsigned short* __restrict__ Wb, const unsigned short* __restrict__ At,
    const float* __restrict__ bias, float* __restrict__ out) {
  extern __shared__ char lds[];
  const int tid = threadIdx.x;
  const int l = tid & 63;
  const int wid = tid >> 6;
  const int wm = wid >> 2;
  const int wn = wid & 3;
  const int nb = blockIdx.x, ob = blockIdx.y, b = blockIdx.z;

  const int rr = tid >> 3;
  const int cswz = ((tid & 7) ^ (rr & 7)) << 3;
  const unsigned short* gA = Wb + (size_t)(ob * 256 + rr) * KPAD + cswz;
  const unsigned short* gB = At + ((size_t)b * HW_ + nb * 256 + rr) * KPAD + cswz;
  char* const dBase = (char*)lds + tid * 16;

#define ISSUE_A(bf, kt)                                         \
  do {                                                          \
    const unsigned short* _s = gA + (kt) * 64;                  \
    char* _d = dBase + (bf) * 65536;                            \
    async16(_s, _d);                                            \
    async16(_s + (size_t)64 * KPAD, _d + 8192);                 \
    async16(_s + (size_t)128 * KPAD, _d + 16384);               \
    async16(_s + (size_t)192 * KPAD, _d + 24576);               \
  } while (0)

#define ISSUE_B(bf, kt)                                         \
  do {                                                          \
    const unsigned short* _s = gB + (kt) * 64;                  \
    char* _d = dBase + (bf) * 65536 + 32768;                    \
    async16(_s, _d);                                            \
    async16(_s + (size_t)64 * KPAD, _d + 8192);                 \
    async16(_s + (size_t)128 * KPAD, _d + 16384);               \
    async16(_s + (size_t)192 * KPAD, _d + 24576);               \
  } while (0)

  const int l15 = l & 15, l4g = l >> 4, l7 = l & 7;
  const int aoff0 = l15 * 128 + ((l4g ^ l7) << 4);
  const int aoff1 = l15 * 128 + (((l4g + 4) ^ l7) << 4);
  const char* aB0 = (const char*)lds + wm * 16384;
  const char* bB0 = (const char*)lds + 32768 + (wn >> 1) * 16384 + (wn & 1) * 8192;

  floatx4 acc[8][4];
#pragma unroll
  for (int i = 0; i < 8; ++i)
#pragma unroll
    for (int j = 0; j < 4; ++j) acc[i][j] = (floatx4){0.f, 0.f, 0.f, 0.f};

  ISSUE_A(0, 0); ISSUE_B(0, 0);
  ISSUE_A(1, 1); ISSUE_B(1, 1);
  asm volatile("s_waitcnt vmcnt(8)" ::: "memory");
  __builtin_amdgcn_s_barrier();

  short8x a[4][2], b0[2][2], b1[2][2];

  for (int t = 0; t < NT; ++t) {
    const int bf = t & 1;
    const char* ab = aB0 + bf * 65536;
    const char* bb = bB0 + bf * 65536;
    const int t2 = (t < NT - 2) ? (t + 2) : 0;

    // ---- P1: read Aq0 + Bh0; MFMA Q00 ----
#pragma unroll
    for (int i = 0; i < 4; ++i) {
      a[i][0] = rd16(ab + i * 2048 + aoff0);
      a[i][1] = rd16(ab + i * 2048 + aoff1);
    }
#pragma unroll
    for (int j = 0; j < 2; ++j) {
      b0[j][0] = rd16(bb + j * 2048 + aoff0);
      b0[j][1] = rd16(bb + j * 2048 + aoff1);
    }
    __builtin_amdgcn_s_barrier();
    asm volatile("s_waitcnt lgkmcnt(0)" ::: "memory");
    __builtin_amdgcn_sched_barrier(0);
    __builtin_amdgcn_s_setprio(1);
#pragma unroll
    for (int i = 0; i < 4; ++i)
#pragma unroll
      for (int j = 0; j < 2; ++j) {
        acc[i][j] = __builtin_amdgcn_mfma_f32_16x16x32_bf16(a[i][0], b0[j][0], acc[i][j], 0, 0, 0);
        acc[i][j] = __builtin_amdgcn_mfma_f32_16x16x32_bf16(a[i][1], b0[j][1], acc[i][j], 0, 0, 0);
      }
    __builtin_amdgcn_s_setprio(0);
    __builtin_amdgcn_s_barrier();

    // ---- P2: read Bh1; MFMA Q01 ----
#pragma unroll
    for (int j = 0; j < 2; ++j) {
      b1[j][0] = rd16(bb + (2 + j) * 2048 + aoff0);
      b1[j][1] = rd16(bb + (2 + j) * 2048 + aoff1);
    }
    __builtin_amdgcn_s_barrier();
    asm volatile("s_waitcnt lgkmcnt(0)" ::: "memory");
    __builtin_amdgcn_sched_barrier(0);
    __builtin_amdgcn_s_setprio(1);
#pragma unroll
    for (int i = 0; i < 4; ++i)
#pragma unroll
      for (int j = 0; j < 2; ++j) {
        acc[i][2 + j] = __builtin_amdgcn_mfma_f32_16x16x32_bf16(a[i][0], b1[j][0], acc[i][2 + j], 0, 0, 0);
        acc[i][2 + j] = __builtin_amdgcn_mfma_f32_16x16x32_bf16(a[i][1], b1[j][1], acc[i][2 + j], 0, 0, 0);
      }
    __builtin_amdgcn_s_setprio(0);
    __builtin_amdgcn_s_barrier();

    // ---- P3: read Aq1; issue B(t+2); MFMA Q11 ----
#pragma unroll
    for (int i = 0; i < 4; ++i) {
      a[i][0] = rd16(ab + (4 + i) * 2048 + aoff0);
      a[i][1] = rd16(ab + (4 + i) * 2048 + aoff1);
    }
    ISSUE_B(bf, t2);
    __builtin_amdgcn_s_barrier();
    asm volatile("s_waitcnt lgkmcnt(0)" ::: "memory");
    __builtin_amdgcn_sched_barrier(0);
    __builtin_amdgcn_s_setprio(1);
#pragma unroll
    for (int i = 0; i < 4; ++i)
#pragma unroll
      for (int j = 0; j < 2; ++j) {
        acc[4 + i][2 + j] = __builtin_amdgcn_mfma_f32_16x16x32_bf16(a[i][0], b1[j][0], acc[4 + i][2 + j], 0, 0, 0);
        acc[4 + i][2 + j] = __builtin_amdgcn_mfma_f32_16x16x32_bf16(a[i][1], b1[j][1], acc[4 + i][2 + j], 0, 0, 0);
      }
    __builtin_amdgcn_s_setprio(0);
    __builtin_amdgcn_s_barrier();

    // ---- P4: issue A(t+2); MFMA Q10; counted vmcnt(8) ----
    ISSUE_A(bf, t2);
    __builtin_amdgcn_s_barrier();
    __builtin_amdgcn_s_setprio(1);
#pragma unroll
    for (int i = 0; i < 4; ++i)
#pragma unroll
      for (int j = 0; j < 2; ++j) {
        acc[4 + i][j] = __builtin_amdgcn_mfma_f32_16x16x32_bf16(a[i][0], b0[j][0], acc[4 + i][j], 0, 0, 0);
        acc[4 + i][j] = __builtin_amdgcn_mfma_f32_16x16x32_bf16(a[i][1], b0[j][1], acc[4 + i][j], 0, 0, 0);
      }
    __builtin_amdgcn_s_setprio(0);
    asm volatile("s_waitcnt vmcnt(8)" ::: "memory");
    __builtin_amdgcn_s_barrier();
  }
  asm volatile("s_waitcnt vmcnt(0)" ::: "memory");
#undef ISSUE_A
#undef ISSUE_B

  float* outb = out + (size_t)b * C_ * HW_;
#pragma unroll
  for (int i = 0; i < 8; ++i) {
    const int o0 = ob * 256 + wm * 128 + i * 16 + l4g * 4;
    float bs[4];
#pragma unroll
    for (int r = 0; r < 4; ++r) bs[r] = bias[o0 + r];
#pragma unroll
    for (int j = 0; j < 4; ++j) {
      const int m = nb * 256 + wn * 64 + j * 16 + l15;
#pragma unroll
      for (int r = 0; r < 4; ++r) {
        float v = acc[i][j][r] + bs[r];
        outb[(size_t)(o0 + r) * HW_ + m] = v > 0.f ? v : 0.f;
      }
    }
  }
}

// ---- launch ----------------------------------------------------------------
extern "C" void kernel_launch(void* const* d_in, const int* in_sizes, int n_in,
                              void* d_out, int out_size, void* d_ws, size_t ws_size,
                              hipStream_t stream) {
  const float* feature = (const float*)d_in[0];
  const float* conv_w  = (const float*)d_in[1];
  const float* conv_b  = (const float*)d_in[2];
  float* out = (float*)d_out;

  // workspace layout (bytes), total 97,648,640:
  //   At   [32768][1088] bf16 : 0          .. 71,303,168
  //   part [8*25][32768] f32  : 71,303,168 .. 97,517,568
  //   Wb   [1024][1088] bf16  : aliases part (part dead after corr_reduce)
  //   invn [32768] f32        : 97,517,568 .. 97,648,640
  char* ws = (char*)d_ws;
  unsigned short* At = (unsigned short*)(ws);
  float* part        = (float*)(ws + 71303168);
  unsigned short* Wb = (unsigned short*)(ws + 71303168);  // aliases part
  float* invn        = (float*)(ws + 97517568);

  static int gemm_attr_set = 0;
  if (!gemm_attr_set) {
    hipFuncSetAttribute((const void*)scn_gemm,
                        hipFuncAttributeMaxDynamicSharedMemorySize, 131072);
    gemm_attr_set = 1;
  }

  // 4608 blocks: n%9==0 -> corr (512), else transpose (4096 x 2 tiles)
  scn_aux<<<dim3(4608), 512, 0, stream>>>(feature, part, At);
  scn_invn<<<dim3(128), 256, 0, stream>>>(part, invn);
  scn_corr_reduce<<<dim3(16, 8), 256, 0, stream>>>(part, invn, At);
  scn_wcast<<<dim3((1024 * KPAD) / 256), 256, 0, stream>>>(conv_w, Wb);
  scn_gemm<<<dim3(16, 4, 8), 512, 131072, stream>>>(Wb, At, conv_b, out);
}

// Round 5
// 378.969 us; speedup vs baseline: 1.2146x; 1.0245x over previous
//
#include <hip/hip_runtime.h>
#include <hip/hip_bf16.h>

// SpatialContextNet on MI355X (gfx950). Round 8.
// Tail-collapse round. Accounting across R6/R7 shows invn+reduce+wcast+gaps
// ~ 160us (more than the GEMM) for <35MB of traffic -> pure latency/launch
// overhead. Changes vs R7:
//  - part[8*25][32768] ELIMINATED: corr-role blocks atomicAdd partials into
//    cs-reduced corr[25][32768] f32 (3.3MB, hipMemsetAsync-zeroed). Each
//    address gets exactly 8 adds -> no contention.
//  - scn_invn DELETED: reduce2 recomputes inv-norms from corr[12] with an
//    8-row LDS halo per block (neighbor invn = LDS hit).
//  - scn_wcast DELETED as a launch: Wb de-aliased (workspace has room now),
//    wcast is a third role inside aux.
//  - transpose role: float4 loads (R5's one good piece).
//  - GEMM: exact R4 kernel (93us verified; MfmaUtil 31%, conflicts 0).
// Chain: memset -> aux -> reduce2 -> gemm  (4 graph nodes, was 6).
//
// feature [8,1024,64,64] f32, conv_w [1024,1049] f32, conv_b [1024] f32.
// Out [8,1024,64,64] f32.

typedef __attribute__((ext_vector_type(8))) short short8x;
typedef __attribute__((ext_vector_type(4))) float floatx4;

#define B_   8
#define C_   1024
#define HW_  4096
#define KPAD 1088
#define NT   17

__device__ __forceinline__ unsigned short f2bf(float f) {
  unsigned int u = __float_as_uint(f);
  u += 0x7FFFu + ((u >> 16) & 1u);
  return (unsigned short)(u >> 16);
}

__device__ __forceinline__ void async16(const void* g, void* l) {
  __builtin_amdgcn_global_load_lds(
      (__attribute__((address_space(1))) void*)(void*)g,
      (__attribute__((address_space(3))) void*)l, 16, 0, 0);
}

__device__ __forceinline__ short8x rd16(const char* p) {
  return *(const short8x*)p;
}

// ---- K1: merged aux: corr partials (atomic) + transpose-cast + wcast -------
// grid 4880 x 512. n<4608: n%9==0 -> corr (512 blocks), else transpose
// (4096 blocks, 2 tiles each). n>=4608: wcast (272 blocks, 8 elems/thread).
// corr: atomicAdd into corr[j*32768 + b*4096 + y*64 + wx] (rotated store).
__global__ __launch_bounds__(512) void scn_aux(
    const float* __restrict__ f, float* __restrict__ corr,
    unsigned short* __restrict__ At, const float* __restrict__ w,
    unsigned short* __restrict__ Wb) {
  __shared__ float lds2[2][64][65];
  const int n = blockIdx.x;
  const int tid = threadIdx.x;

  if (n >= 4608) {
    // ================= wcast role: conv_w f32 -> Wb bf16, pad to 1088 ======
    const int base = (n - 4608) * 4096 + tid * 8;
    const int o = base / KPAD, kk = base - o * KPAD;
    short8x v;
#pragma unroll
    for (int e = 0; e < 8; ++e) {
      const int k = kk + e;
      v[e] = (k < 1049) ? (short)f2bf(w[(size_t)o * 1049 + k]) : (short)0;
    }
    *(short8x*)(Wb + (size_t)o * KPAD + kk) = v;
    return;
  }

  const int g = n / 9, r = n - g * 9;
  if (r == 0) {
    // ================= corr role (R7 body, atomic cs-reduced store) ========
    const int x = tid & 63;
    const int y = (g & 7) * 8 + (tid >> 6);
    const int cs = (g >> 3) & 7, b = g >> 6;

    const int xs0 = (x + 2 < 64) ? x + 2 : 63;
    const int xs1 = (x + 1 < 64) ? x + 1 : 63;
    const int xs3 = (x - 1 >= 0) ? x - 1 : 0;
    const int xs4 = (x - 2 >= 0) ? x - 2 : 0;

    const bool ym2 = (y >= 2), ym1 = (y >= 1), yp1 = (y <= 62), yp2 = (y <= 61);

    const float* rp0 = f + ((size_t)b * C_ + cs * 128) * HW_ + y * 64;

    float h[25];
#pragma unroll
    for (int j = 0; j < 25; ++j) h[j] = 0.f;

#pragma unroll 4
    for (int c = 0; c < 128; ++c) {
      const float* rp = rp0 + (size_t)c * HW_;
      const float ctr = rp[x];
      const float vm2 = ym2 ? rp[x - 128] : 0.f;
      const float vm1 = ym1 ? rp[x - 64] : 0.f;
      const float vp1 = yp1 ? rp[x + 64] : 0.f;
      const float vp2 = yp2 ? rp[x + 128] : 0.f;
      const float c0 = __shfl(ctr, xs0, 64);
      const float c1 = __shfl(ctr, xs1, 64);
      const float c3 = __shfl(ctr, xs3, 64);
      const float c4 = __shfl(ctr, xs4, 64);
      const float v[5] = {vm2, vm1, ctr, vp1, vp2};
      const float cc[5] = {c0, c1, ctr, c3, c4};
#pragma unroll
      for (int dxi = 0; dxi < 5; ++dxi)
#pragma unroll
        for (int dyi = 0; dyi < 5; ++dyi)
          h[dxi * 5 + dyi] = fmaf(v[dyi], cc[dxi], h[dxi * 5 + dyi]);
    }

    float* pb = corr + b * HW_ + y * 64;
#pragma unroll
    for (int j = 0; j < 25; ++j) {
      const int dx = (j / 5) - 2;
      const int tgt = x - dx;
      const int wx = (tgt + 64) & 63;
      const float val = ((unsigned)tgt < 64u) ? h[j] : 0.f;
      atomicAdd(pb + (size_t)j * 32768 + wx, val);
    }
  } else {
    // ================= transpose role (float4 loads, 2 tiles/block) ========
    const int half = tid >> 8, t256 = tid & 255;
    const int tile = (g * 8 + (r - 1)) * 2 + half;
    const int b = tile >> 10, rem = tile & 1023;
    const int kt = rem >> 6, mt = rem & 63;

    const int m4 = (t256 & 15) << 2, kr0 = t256 >> 4;
    const float* src = f + ((size_t)b * C_ + kt * 64 + kr0) * HW_ + mt * 64 + m4;
#pragma unroll
    for (int i = 0; i < 4; ++i) {
      floatx4 v = *(const floatx4*)(src + (size_t)i * 16 * HW_);
      float* d = &lds2[half][kr0 + i * 16][m4];
      d[0] = v[0]; d[1] = v[1]; d[2] = v[2]; d[3] = v[3];
    }
    __syncthreads();
    unsigned short* dst = At + ((size_t)b * HW_ + mt * 64) * KPAD + kt * 64;
    const int c = t256 & 7, mr = t256 >> 3;
#pragma unroll
    for (int h2 = 0; h2 < 2; ++h2) {
      const int mm = mr + h2 * 32;
      short8x v;
#pragma unroll
      for (int j = 0; j < 8; ++j) v[j] = (short)f2bf(lds2[half][c * 8 + j][mm]);
      *(short8x*)(dst + (size_t)mm * KPAD + c * 8) = v;
    }
  }
}

// ---- K2: reduce2 — invn from corr[12] halo (LDS) + At rows 1024..1087 ------
// grid (16, 8), block 256 (4 y-rows per block, 8-row invn halo in LDS).
__global__ __launch_bounds__(256) void scn_reduce2(
    const float* __restrict__ corr, unsigned short* __restrict__ At) {
  __shared__ float linv[8][64];
  const int b = blockIdx.y;
  const int bx = blockIdx.x;
  const int tid = threadIdx.x;
  const int x = tid & 63;
  const int y0 = bx * 4;

  // halo inv-norms: rows y0-2 .. y0+5
  const float* c12 = corr + (size_t)12 * 32768 + b * HW_;
#pragma unroll
  for (int rr = 0; rr < 2; ++rr) {
    const int rsel = (tid >> 6) + rr * 4;        // 0..7
    const int yy = y0 - 2 + rsel;
    const float s = (yy >= 0 && yy < 64) ? c12[yy * 64 + x] : 1.0f;
    linv[rsel][x] = 1.0f / fmaxf(sqrtf(s), 1e-12f);
  }
  __syncthreads();

  const int m = bx * 256 + tid;
  const int i = b * HW_ + m;
  const int yr = tid >> 6;  // 0..3, y = y0+yr
  const float ic = linv[yr + 2][x];

  unsigned short r[64];
#pragma unroll
  for (int j = 0; j < 25; ++j) {
    const float acc = corr[(size_t)j * 32768 + i];
    const int dy = (j % 5) - 2, dx = (j / 5) - 2;
    const int ny = y0 + yr + dy, nx = x + dx;
    const float in2 = (ny >= 0 && ny < 64 && nx >= 0 && nx < 64)
                          ? linv[yr + 2 + dy][nx] : 0.f;
    r[j] = f2bf(acc * ic * in2);
  }
#pragma unroll
  for (int j = 25; j < 64; ++j) r[j] = 0;
  unsigned short* row = At + ((size_t)b * HW_ + m) * KPAD + 1024;
#pragma unroll
  for (int v = 0; v < 8; ++v) *(short8x*)(row + v * 8) = *(short8x*)(r + v * 8);
}

// ---- K3: bf16 MFMA GEMM 256x256/BK=64, pipelined (exact Round-4 kernel) ----
// grid (16 nb, 4 ob, 8 b), block 512 (8 waves: wm = wid>>2, wn = wid&3).
// LDS 128 KiB: buf[2] x { A: 2 halves x [128][64] ; B: same }, bf16.
// Staging: global_load_lds, linear dest, inverse-swizzled global source.
// Read swizzle: 16B slot ^= (row&7). Counted vmcnt(8), raw s_barrier only.
__global__ __launch_bounds__(512, 2) void scn_gemm(
    const unsigned short* __restrict__ Wb, const unsigned short* __restrict__ At,
    const float* __restrict__ bias, float* __restrict__ out) {
  extern __shared__ char lds[];
  const int tid = threadIdx.x;
  const int l = tid & 63;
  const int wid = tid >> 6;
  const int wm = wid >> 2;
  const int wn = wid & 3;
  const int nb = blockIdx.x, ob = blockIdx.y, b = blockIdx.z;

  const int rr = tid >> 3;
  const int cswz = ((tid & 7) ^ (rr & 7)) << 3;
  const unsigned short* gA = Wb + (size_t)(ob * 256 + rr) * KPAD + cswz;
  const unsigned short* gB = At + ((size_t)b * HW_ + nb * 256 + rr) * KPAD + cswz;
  char* const dBase = (char*)lds + tid * 16;

#define ISSUE_A(bf, kt)                                         \
  do {                                                          \
    const unsigned short* _s = gA + (kt) * 64;                  \
    char* _d = dBase + (bf) * 65536;                            \
    async16(_s, _d);                                            \
    async16(_s + (size_t)64 * KPAD, _d + 8192);                 \
    async16(_s + (size_t)128 * KPAD, _d + 16384);               \
    async16(_s + (size_t)192 * KPAD, _d + 24576);               \
  } while (0)

#define ISSUE_B(bf, kt)                                         \
  do {                                                          \
    const unsigned short* _s = gB + (kt) * 64;                  \
    char* _d = dBase + (bf) * 65536 + 32768;                    \
    async16(_s, _d);                                            \
    async16(_s + (size_t)64 * KPAD, _d + 8192);                 \
    async16(_s + (size_t)128 * KPAD, _d + 16384);               \
    async16(_s + (size_t)192 * KPAD, _d + 24576);               \
  } while (0)

  const int l15 = l & 15, l4g = l >> 4, l7 = l & 7;
  const int aoff0 = l15 * 128 + ((l4g ^ l7) << 4);
  const int aoff1 = l15 * 128 + (((l4g + 4) ^ l7) << 4);
  const char* aB0 = (const char*)lds + wm * 16384;
  const char* bB0 = (const char*)lds + 32768 + (wn >> 1) * 16384 + (wn & 1) * 8192;

  floatx4 acc[8][4];
#pragma unroll
  for (int i = 0; i < 8; ++i)
#pragma unroll
    for (int j = 0; j < 4; ++j) acc[i][j] = (floatx4){0.f, 0.f, 0.f, 0.f};

  ISSUE_A(0, 0); ISSUE_B(0, 0);
  ISSUE_A(1, 1); ISSUE_B(1, 1);
  asm volatile("s_waitcnt vmcnt(8)" ::: "memory");
  __builtin_amdgcn_s_barrier();

  short8x a[4][2], b0[2][2], b1[2][2];

  for (int t = 0; t < NT; ++t) {
    const int bf = t & 1;
    const char* ab = aB0 + bf * 65536;
    const char* bb = bB0 + bf * 65536;
    const int t2 = (t < NT - 2) ? (t + 2) : 0;

    // ---- P1: read Aq0 + Bh0; MFMA Q00 ----
#pragma unroll
    for (int i = 0; i < 4; ++i) {
      a[i][0] = rd16(ab + i * 2048 + aoff0);
      a[i][1] = rd16(ab + i * 2048 + aoff1);
    }
#pragma unroll
    for (int j = 0; j < 2; ++j) {
      b0[j][0] = rd16(bb + j * 2048 + aoff0);
      b0[j][1] = rd16(bb + j * 2048 + aoff1);
    }
    __builtin_amdgcn_s_barrier();
    asm volatile("s_waitcnt lgkmcnt(0)" ::: "memory");
    __builtin_amdgcn_sched_barrier(0);
    __builtin_amdgcn_s_setprio(1);
#pragma unroll
    for (int i = 0; i < 4; ++i)
#pragma unroll
      for (int j = 0; j < 2; ++j) {
        acc[i][j] = __builtin_amdgcn_mfma_f32_16x16x32_bf16(a[i][0], b0[j][0], acc[i][j], 0, 0, 0);
        acc[i][j] = __builtin_amdgcn_mfma_f32_16x16x32_bf16(a[i][1], b0[j][1], acc[i][j], 0, 0, 0);
      }
    __builtin_amdgcn_s_setprio(0);
    __builtin_amdgcn_s_barrier();

    // ---- P2: read Bh1; MFMA Q01 ----
#pragma unroll
    for (int j = 0; j < 2; ++j) {
      b1[j][0] = rd16(bb + (2 + j) * 2048 + aoff0);
      b1[j][1] = rd16(bb + (2 + j) * 2048 + aoff1);
    }
    __builtin_amdgcn_s_barrier();
    asm volatile("s_waitcnt lgkmcnt(0)" ::: "memory");
    __builtin_amdgcn_sched_barrier(0);
    __builtin_amdgcn_s_setprio(1);
#pragma unroll
    for (int i = 0; i < 4; ++i)
#pragma unroll
      for (int j = 0; j < 2; ++j) {
        acc[i][2 + j] = __builtin_amdgcn_mfma_f32_16x16x32_bf16(a[i][0], b1[j][0], acc[i][2 + j], 0, 0, 0);
        acc[i][2 + j] = __builtin_amdgcn_mfma_f32_16x16x32_bf16(a[i][1], b1[j][1], acc[i][2 + j], 0, 0, 0);
      }
    __builtin_amdgcn_s_setprio(0);
    __builtin_amdgcn_s_barrier();

    // ---- P3: read Aq1; issue B(t+2); MFMA Q11 ----
#pragma unroll
    for (int i = 0; i < 4; ++i) {
      a[i][0] = rd16(ab + (4 + i) * 2048 + aoff0);
      a[i][1] = rd16(ab + (4 + i) * 2048 + aoff1);
    }
    ISSUE_B(bf, t2);
    __builtin_amdgcn_s_barrier();
    asm volatile("s_waitcnt lgkmcnt(0)" ::: "memory");
    __builtin_amdgcn_sched_barrier(0);
    __builtin_amdgcn_s_setprio(1);
#pragma unroll
    for (int i = 0; i < 4; ++i)
#pragma unroll
      for (int j = 0; j < 2; ++j) {
        acc[4 + i][2 + j] = __builtin_amdgcn_mfma_f32_16x16x32_bf16(a[i][0], b1[j][0], acc[4 + i][2 + j], 0, 0, 0);
        acc[4 + i][2 + j] = __builtin_amdgcn_mfma_f32_16x16x32_bf16(a[i][1], b1[j][1], acc[4 + i][2 + j], 0, 0, 0);
      }
    __builtin_amdgcn_s_setprio(0);
    __builtin_amdgcn_s_barrier();

    // ---- P4: issue A(t+2); MFMA Q10; counted vmcnt(8) ----
    ISSUE_A(bf, t2);
    __builtin_amdgcn_s_barrier();
    __builtin_amdgcn_s_setprio(1);
#pragma unroll
    for (int i = 0; i < 4; ++i)
#pragma unroll
      for (int j = 0; j < 2; ++j) {
        acc[4 + i][j] = __builtin_amdgcn_mfma_f32_16x16x32_bf16(a[i][0], b0[j][0], acc[4 + i][j], 0, 0, 0);
        acc[4 + i][j] = __builtin_amdgcn_mfma_f32_16x16x32_bf16(a[i][1], b0[j][1], acc[4 + i][j], 0, 0, 0);
      }
    __builtin_amdgcn_s_setprio(0);
    asm volatile("s_waitcnt vmcnt(8)" ::: "memory");
    __builtin_amdgcn_s_barrier();
  }
  asm volatile("s_waitcnt vmcnt(0)" ::: "memory");
#undef ISSUE_A
#undef ISSUE_B

  float* outb = out + (size_t)b * C_ * HW_;
#pragma unroll
  for (int i = 0; i < 8; ++i) {
    const int o0 = ob * 256 + wm * 128 + i * 16 + l4g * 4;
    float bs[4];
#pragma unroll
    for (int r = 0; r < 4; ++r) bs[r] = bias[o0 + r];
#pragma unroll
    for (int j = 0; j < 4; ++j) {
      const int m = nb * 256 + wn * 64 + j * 16 + l15;
#pragma unroll
      for (int r = 0; r < 4; ++r) {
        float v = acc[i][j][r] + bs[r];
        outb[(size_t)(o0 + r) * HW_ + m] = v > 0.f ? v : 0.f;
      }
    }
  }
}

// ---- launch ----------------------------------------------------------------
extern "C" void kernel_launch(void* const* d_in, const int* in_sizes, int n_in,
                              void* d_out, int out_size, void* d_ws, size_t ws_size,
                              hipStream_t stream) {
  const float* feature = (const float*)d_in[0];
  const float* conv_w  = (const float*)d_in[1];
  const float* conv_b  = (const float*)d_in[2];
  float* out = (float*)d_out;

  // workspace layout (bytes), total 76,808,192:
  //   At   [32768][1088] bf16 : 0          .. 71,303,168
  //   corr [25][32768] f32    : 71,303,168 .. 74,579,968  (memset each call)
  //   Wb   [1024][1088] bf16  : 74,579,968 .. 76,808,192  (no aliasing)
  char* ws = (char*)d_ws;
  unsigned short* At = (unsigned short*)(ws);
  float* corr        = (float*)(ws + 71303168);
  unsigned short* Wb = (unsigned short*)(ws + 74579968);

  static int gemm_attr_set = 0;
  if (!gemm_attr_set) {
    hipFuncSetAttribute((const void*)scn_gemm,
                        hipFuncAttributeMaxDynamicSharedMemorySize, 131072);
    gemm_attr_set = 1;
  }

  hipMemsetAsync(corr, 0, 25 * 32768 * sizeof(float), stream);
  // 4880 blocks: n<4608 -> corr/transpose (1:8), n>=4608 -> wcast (272)
  scn_aux<<<dim3(4880), 512, 0, stream>>>(feature, corr, At, conv_w, Wb);
  scn_reduce2<<<dim3(16, 8), 256, 0, stream>>>(corr, At);
  scn_gemm<<<dim3(16, 4, 8), 512, 131072, stream>>>(Wb, At, conv_b, out);
}